// Round 1
// baseline (3290.196 us; speedup 1.0000x reference)
//
#include <hip/hip_runtime.h>
#include <hip/hip_bf16.h>
#include <math.h>

namespace {

constexpr int kB = 2;
constexpr int kS = 2048;
constexpr int kH = 4096;
constexpr int kNH = 16;
constexpr int kHD = 256;

typedef __attribute__((ext_vector_type(4))) float f32x4;
typedef __attribute__((ext_vector_type(8))) short bf16x8;

__device__ __forceinline__ unsigned short f2bf(float f) {
  unsigned int u = __float_as_uint(f);
  u += 0x7FFFu + ((u >> 16) & 1u);
  return (unsigned short)(u >> 16);
}
__device__ __forceinline__ float bf2f(unsigned short h) {
  return __uint_as_float(((unsigned int)h) << 16);
}
__device__ __forceinline__ void gl2lds16(const void* g, void* l) {
  __builtin_amdgcn_global_load_lds(
      (const __attribute__((address_space(1))) unsigned int*)g,
      (__attribute__((address_space(3))) unsigned int*)l, 16, 0, 0);
}

// ---------------- LayerNorm: x -> h(bf16), out = x (residual init) ---------
__global__ __launch_bounds__(256) void ln_fwd(
    const float* __restrict__ x, const float* __restrict__ gam,
    const float* __restrict__ bet, unsigned short* __restrict__ hout,
    float* __restrict__ outp) {
  int row = blockIdx.x;
  int t = threadIdx.x;
  const float4* xr = (const float4*)(x + (size_t)row * kH);
  float4 v[4];
  float sum = 0.f, sq = 0.f;
#pragma unroll
  for (int i = 0; i < 4; i++) {
    v[i] = xr[t + i * 256];
    sum += v[i].x + v[i].y + v[i].z + v[i].w;
    sq += v[i].x * v[i].x + v[i].y * v[i].y + v[i].z * v[i].z + v[i].w * v[i].w;
  }
#pragma unroll
  for (int o = 32; o > 0; o >>= 1) {
    sum += __shfl_xor(sum, o);
    sq += __shfl_xor(sq, o);
  }
  __shared__ float red[8];
  if ((t & 63) == 0) { red[t >> 6] = sum; red[4 + (t >> 6)] = sq; }
  __syncthreads();
  sum = red[0] + red[1] + red[2] + red[3];
  sq = red[4] + red[5] + red[6] + red[7];
  float mu = sum * (1.f / kH);
  float rstd = rsqrtf(sq * (1.f / kH) - mu * mu + 1e-5f);
  const float4* gp = (const float4*)gam;
  const float4* bp = (const float4*)bet;
  ushort4* hr = (ushort4*)(hout + (size_t)row * kH);
  float4* orow = (float4*)(outp + (size_t)row * kH);
#pragma unroll
  for (int i = 0; i < 4; i++) {
    float4 g = gp[t + i * 256];
    float4 bb = bp[t + i * 256];
    ushort4 hv;
    hv.x = f2bf((v[i].x - mu) * rstd * g.x + bb.x);
    hv.y = f2bf((v[i].y - mu) * rstd * g.y + bb.y);
    hv.z = f2bf((v[i].z - mu) * rstd * g.z + bb.z);
    hv.w = f2bf((v[i].w - mu) * rstd * g.w + bb.w);
    hr[t + i * 256] = hv;
    orow[t + i * 256] = v[i];
  }
}

// ------- transpose-convert: out[n][k] = bf16(in[k][n]) ---------------------
__global__ __launch_bounds__(256) void cvt_t(
    const float* __restrict__ in, int ldin, unsigned short* __restrict__ outp,
    int ldout) {
  __shared__ float tile[32][33];
  int n0 = blockIdx.x * 32, k0 = blockIdx.y * 32;
  int tx = threadIdx.x, ty = threadIdx.y;
#pragma unroll
  for (int i = 0; i < 4; i++)
    tile[ty + i * 8][tx] = in[(size_t)(k0 + ty + i * 8) * ldin + n0 + tx];
  __syncthreads();
#pragma unroll
  for (int i = 0; i < 4; i++)
    outp[(size_t)(n0 + ty + i * 8) * ldout + k0 + tx] =
        f2bf(tile[tx][ty + i * 8]);
}

// ------- v [B,S,NH,HD] -> vt [B,NH,HD,S] (bf16) ----------------------------
__global__ __launch_bounds__(256) void vtrans(
    const unsigned short* __restrict__ v, unsigned short* __restrict__ vt) {
  __shared__ unsigned short tile[32][33];
  int bh = blockIdx.z;
  int s0 = blockIdx.x * 32, d0 = blockIdx.y * 32;
  int tx = threadIdx.x, ty = threadIdx.y;
  int b = bh >> 4, h = bh & 15;
  const unsigned short* src = v + (size_t)(b * kS) * kH + h * kHD;
#pragma unroll
  for (int i = 0; i < 4; i++)
    tile[ty + i * 8][tx] = src[(size_t)(s0 + ty + i * 8) * kH + d0 + tx];
  __syncthreads();
  unsigned short* dst = vt + (size_t)bh * kHD * kS;
#pragma unroll
  for (int i = 0; i < 4; i++)
    dst[(size_t)(d0 + ty + i * 8) * kS + s0 + tx] = tile[tx][ty + i * 8];
}

// ------- RoPE (pairs) + q-scale 1/16, in place -----------------------------
__global__ __launch_bounds__(256) void rope_scale(
    unsigned short* __restrict__ q, unsigned short* __restrict__ k,
    const int* __restrict__ pos) {
  int idx = blockIdx.x * 256 + threadIdx.x;  // pair index over B*S*NH*(HD/2)
  int j = idx & 127;
  int rowh = idx >> 7;  // b*S*NH + s*NH + h
  int h = rowh & 15;
  int s = (rowh >> 4) & 2047;
  int b = rowh >> 15;
  size_t off = ((size_t)(b * kS + s)) * kH + h * kHD + 2 * j;
  const float SCALE = 0.0625f;  // 1/sqrt(256)
  if (j < 32) {
    int p = pos[b * kS + s];
    float inv = exp2f(-(float)j * (13.287712379549449f / 32.f));  // 10000^(-j/32)
    float fr = (float)p * inv;
    float sn, cs;
    sincosf(fr, &sn, &cs);
    float e = bf2f(q[off]), o = bf2f(q[off + 1]);
    q[off] = f2bf((e * cs - o * sn) * SCALE);
    q[off + 1] = f2bf((o * cs + e * sn) * SCALE);
    e = bf2f(k[off]); o = bf2f(k[off + 1]);
    k[off] = f2bf(e * cs - o * sn);
    k[off + 1] = f2bf(o * cs + e * sn);
  } else {
    q[off] = f2bf(bf2f(q[off]) * SCALE);
    q[off + 1] = f2bf(bf2f(q[off + 1]) * SCALE);
  }
}

// ------- GEMM: C[M][N] = A[M][K] * Bt[N][K]^T, 128x128 tile, BK=32 ---------
// EPI 0: bf16 store. 1: bf16(gelu(v+bias[n])). 2: Cf[idx]+=v. 3: +=v+bias[n].
template <int EPI>
__global__ __launch_bounds__(256) void gemm_bt(
    const unsigned short* __restrict__ A, int lda,
    const unsigned short* __restrict__ Bt, int ldb, void* __restrict__ Cp,
    int ldc, const float* __restrict__ bias, int K) {
  __shared__ unsigned short sA[128 * 32];
  __shared__ unsigned short sB[128 * 32];
  int t = threadIdx.x;
  int lane = t & 63, w = t >> 6;
  int wr = w >> 1, wc = w & 1;
  int m0 = blockIdx.y * 128, n0 = blockIdx.x * 128;

  int arow = t >> 2;                       // 0..63
  int achk = (t & 3) ^ ((arow >> 1) & 3);  // swizzled source chunk
  const unsigned short* aG0 = A + (size_t)(m0 + arow) * lda + achk * 8;
  const unsigned short* aG1 = A + (size_t)(m0 + arow + 64) * lda + achk * 8;
  const unsigned short* bG0 = Bt + (size_t)(n0 + arow) * ldb + achk * 8;
  const unsigned short* bG1 = Bt + (size_t)(n0 + arow + 64) * ldb + achk * 8;
  unsigned short* sA0 = sA + t * 8;
  unsigned short* sA1 = sA + 2048 + t * 8;
  unsigned short* sB0 = sB + t * 8;
  unsigned short* sB1 = sB + 2048 + t * 8;

  int afo[4], bfo[4];
#pragma unroll
  for (int m = 0; m < 4; m++) {
    int row = wr * 64 + m * 16 + (lane & 15);
    afo[m] = row * 32 + (((lane >> 4) ^ ((row >> 1) & 3)) * 8);
    int rowb = wc * 64 + m * 16 + (lane & 15);
    bfo[m] = rowb * 32 + (((lane >> 4) ^ ((rowb >> 1) & 3)) * 8);
  }
  f32x4 acc[4][4];
#pragma unroll
  for (int m = 0; m < 4; m++)
#pragma unroll
    for (int n = 0; n < 4; n++) acc[m][n] = (f32x4)(0.f);

  for (int kt = 0; kt < K; kt += 32) {
    __syncthreads();
    gl2lds16(aG0, sA0);
    gl2lds16(aG1, sA1);
    gl2lds16(bG0, sB0);
    gl2lds16(bG1, sB1);
    aG0 += 32; aG1 += 32; bG0 += 32; bG1 += 32;
    __syncthreads();
    bf16x8 af[4], bf[4];
#pragma unroll
    for (int m = 0; m < 4; m++) af[m] = *(const bf16x8*)&sA[afo[m]];
#pragma unroll
    for (int n = 0; n < 4; n++) bf[n] = *(const bf16x8*)&sB[bfo[n]];
#pragma unroll
    for (int m = 0; m < 4; m++)
#pragma unroll
      for (int n = 0; n < 4; n++)
        acc[m][n] =
            __builtin_amdgcn_mfma_f32_16x16x32_bf16(af[m], bf[n], acc[m][n], 0, 0, 0);
  }

  int grow = m0 + wr * 64, gcol = n0 + wc * 64;
#pragma unroll
  for (int m = 0; m < 4; m++) {
#pragma unroll
    for (int n = 0; n < 4; n++) {
      int col = gcol + n * 16 + (lane & 15);
#pragma unroll
      for (int r = 0; r < 4; r++) {
        int row = grow + m * 16 + ((lane >> 4) << 2) + r;
        float v = acc[m][n][r];
        size_t idx = (size_t)row * ldc + col;
        if constexpr (EPI == 0) {
          ((unsigned short*)Cp)[idx] = f2bf(v);
        } else if constexpr (EPI == 1) {
          float u = v + bias[col];
          float c = 0.7978845608028654f * (u + 0.044715f * u * u * u);
          float g = u / (1.0f + __expf(-2.0f * c));  // u*0.5*(1+tanh(c))
          ((unsigned short*)Cp)[idx] = f2bf(g);
        } else if constexpr (EPI == 2) {
          ((float*)Cp)[idx] += v;
        } else {
          ((float*)Cp)[idx] += v + bias[col];
        }
      }
    }
  }
}

// ------- flash attention: 4 waves x 16 q-rows, KVBLK=32, HD=256 ------------
__global__ __launch_bounds__(256) void attn_fwd(
    const unsigned short* __restrict__ q, const unsigned short* __restrict__ k,
    const unsigned short* __restrict__ vt, const int* __restrict__ amask,
    unsigned short* __restrict__ ctx) {
  __shared__ unsigned short sK[32 * 256];   // [kv][d], 512B rows, swz row&7
  __shared__ unsigned short sV[256 * 32];   // [d][kv], 64B rows, swz (row>>1)&3
  __shared__ unsigned short sP[4 * 16 * 32];  // per-wave P, 64B rows
  int t = threadIdx.x, lane = t & 63, w = t >> 6;
  int qb = blockIdx.x, bh = blockIdx.y;
  int b = bh >> 4, h = bh & 15;
  int l15 = lane & 15, l4 = lane >> 4;

  bf16x8 qf[8];
  {
    int qrow = qb * 64 + w * 16 + l15;
    const unsigned short* qp =
        q + (size_t)(b * kS + qrow) * kH + h * kHD + l4 * 8;
#pragma unroll
    for (int ks = 0; ks < 8; ks++) qf[ks] = *(const bf16x8*)(qp + ks * 32);
  }
  f32x4 o[16];
#pragma unroll
  for (int nf = 0; nf < 16; nf++) o[nf] = (f32x4)(0.f);
  float mr[4] = {-INFINITY, -INFINITY, -INFINITY, -INFINITY};
  float lr[4] = {0.f, 0.f, 0.f, 0.f};

  int krow = t >> 5, kchk = t & 31;  // K tile staging
  int vrow = t >> 2, vchk = t & 3;   // V tile staging
  const unsigned short* kbase = k + (size_t)(b * kS) * kH + h * kHD;
  const unsigned short* vbase = vt + (size_t)bh * kHD * kS;
  int ntiles = 2 * qb + 2;

  for (int kvt = 0; kvt < ntiles; kvt++) {
    int kv0 = kvt * 32;
    __syncthreads();
#pragma unroll
    for (int i = 0; i < 4; i++) {
      int row = krow + i * 8;
      int csw = kchk ^ (row & 7);
      gl2lds16(kbase + (size_t)(kv0 + row) * kH + csw * 8,
               (char*)sK + i * 4096 + t * 16);
      int d = vrow + i * 64;
      int csw2 = vchk ^ ((d >> 1) & 3);
      gl2lds16(vbase + (size_t)d * kS + kv0 + csw2 * 8,
               (char*)sV + i * 4096 + t * 16);
    }
    __syncthreads();

    f32x4 sc[2];
    sc[0] = (f32x4)(0.f);
    sc[1] = (f32x4)(0.f);
#pragma unroll
    for (int nf = 0; nf < 2; nf++) {
      int row = nf * 16 + l15;
#pragma unroll
      for (int ks = 0; ks < 8; ks++) {
        int slot = (ks * 4 + l4) ^ (row & 7);
        bf16x8 kf = *(const bf16x8*)&sK[row * 256 + slot * 8];
        sc[nf] = __builtin_amdgcn_mfma_f32_16x16x32_bf16(qf[ks], kf, sc[nf], 0, 0, 0);
      }
    }

    int am0 = amask[b * kS + kv0 + l15];
    int am1 = amask[b * kS + kv0 + 16 + l15];
    int kva = kv0 + l15, kvb = kv0 + 16 + l15;
#pragma unroll
    for (int r = 0; r < 4; r++) {
      int qi = qb * 64 + w * 16 + l4 * 4 + r;
      float s0v = (kva <= qi && am0 != 0) ? sc[0][r] : -INFINITY;
      float s1v = (kvb <= qi && am1 != 0) ? sc[1][r] : -INFINITY;
      float mx = fmaxf(s0v, s1v);
#pragma unroll
      for (int d = 1; d < 16; d <<= 1) mx = fmaxf(mx, __shfl_xor(mx, d));
      float mn = fmaxf(mr[r], mx);
      float corr = __expf(mr[r] - mn);
      float p0 = __expf(s0v - mn);
      float p1 = __expf(s1v - mn);
      float rsum = p0 + p1;
#pragma unroll
      for (int d = 1; d < 16; d <<= 1) rsum += __shfl_xor(rsum, d);
      lr[r] = lr[r] * corr + rsum;
      mr[r] = mn;
#pragma unroll
      for (int nf = 0; nf < 16; nf++) o[nf][r] *= corr;
      int prow = l4 * 4 + r;
      int swz = ((prow >> 1) & 3) << 4;
      int byte0 = prow * 64 + ((l15 * 2) ^ swz);
      int byte1 = prow * 64 + (((16 + l15) * 2) ^ swz);
      sP[w * 512 + (byte0 >> 1)] = f2bf(p0);
      sP[w * 512 + (byte1 >> 1)] = f2bf(p1);
    }

    // PV
    int pslot = l4 ^ ((l15 >> 1) & 3);
    bf16x8 pa = *(const bf16x8*)&sP[w * 512 + l15 * 32 + pslot * 8];
#pragma unroll
    for (int nf = 0; nf < 16; nf++) {
      int vr = nf * 16 + l15;
      int vslot = l4 ^ ((vr >> 1) & 3);
      bf16x8 vf = *(const bf16x8*)&sV[vr * 32 + vslot * 8];
      o[nf] = __builtin_amdgcn_mfma_f32_16x16x32_bf16(pa, vf, o[nf], 0, 0, 0);
    }
  }

  float invl[4];
#pragma unroll
  for (int r = 0; r < 4; r++) invl[r] = 1.0f / lr[r];
#pragma unroll
  for (int nf = 0; nf < 16; nf++) {
    int d = nf * 16 + l15;
#pragma unroll
    for (int r = 0; r < 4; r++) {
      int qi = qb * 64 + w * 16 + l4 * 4 + r;
      ctx[(size_t)(b * kS + qi) * kH + h * kHD + d] = f2bf(o[nf][r] * invl[r]);
    }
  }
}

}  // namespace

extern "C" void kernel_launch(void* const* d_in, const int* in_sizes, int n_in,
                              void* d_out, int out_size, void* d_ws,
                              size_t ws_size, hipStream_t stream) {
  const float* x = (const float*)d_in[0];
  const int* amask = (const int*)d_in[1];
  const int* pos = (const int*)d_in[2];
  const float* lns = (const float*)d_in[3];
  const float* lnb = (const float*)d_in[4];
  const float* wq = (const float*)d_in[5];
  const float* wk = (const float*)d_in[6];
  const float* wv = (const float*)d_in[7];
  const float* wo = (const float*)d_in[8];
  const float* w_in = (const float*)d_in[9];
  const float* b_in = (const float*)d_in[10];
  const float* w_out = (const float*)d_in[11];
  const float* b_out = (const float*)d_in[12];
  float* out = (float*)d_out;

  if (ws_size < 268435456ull) return;  // need 256 MiB scratch
  char* ws = (char*)d_ws;
  unsigned short* h_bf = (unsigned short*)ws;                  // 32 MiB
  unsigned short* big = (unsigned short*)(ws + 33554432ull);   // 128 MiB
  unsigned short* vbuf = (unsigned short*)(ws + 167772160ull); // 32 MiB
  unsigned short* wbuf = (unsigned short*)(ws + 201326592ull); // 64 MiB
  unsigned short* mid = big;                    // [4096][16384] during MLP
  unsigned short* qbuf = big;                   // then q
  unsigned short* kbuf = big + 16777216;        // k
  unsigned short* vtb = big + 33554432;         // v^T [B,NH,HD,S]
  unsigned short* ctxb = vbuf;                  // ctx overwrites v after vtrans

  dim3 t256(256);
  dim3 t32x8(32, 8);

  // 1. LayerNorm -> h (bf16); out = x
  ln_fwd<<<kB * kS, t256, 0, stream>>>(x, lns, lnb, h_bf, out);

  // 2. MLP first GEMM (two N-halves): mid = gelu(h @ w_in + b_in)
  for (int c = 0; c < 2; c++) {
    cvt_t<<<dim3(256, 128), t32x8, 0, stream>>>(w_in + c * 8192, 16384, wbuf, 4096);
    gemm_bt<1><<<dim3(64, 32), t256, 0, stream>>>(
        h_bf, 4096, wbuf, 4096, mid + c * 8192, 16384, b_in + c * 8192, 4096);
  }
  // 3. MLP second GEMM (two K-halves): out += mid @ w_out + b_out
  for (int c = 0; c < 2; c++) {
    cvt_t<<<dim3(128, 256), t32x8, 0, stream>>>(
        w_out + (size_t)c * 8192 * 4096, 4096, wbuf, 8192);
    if (c == 0)
      gemm_bt<3><<<dim3(32, 32), t256, 0, stream>>>(mid + c * 8192, 16384, wbuf,
                                                    8192, out, 4096, b_out, 8192);
    else
      gemm_bt<2><<<dim3(32, 32), t256, 0, stream>>>(
          mid + c * 8192, 16384, wbuf, 8192, out, 4096, nullptr, 8192);
  }

  // 4. QKV projections (mid region is free now; q,k go there, v separate)
  const float* wqkv[3] = {wq, wk, wv};
  unsigned short* qkvp[3] = {qbuf, kbuf, vbuf};
  for (int i = 0; i < 3; i++) {
    cvt_t<<<dim3(128, 128), t32x8, 0, stream>>>(wqkv[i], 4096, wbuf, 4096);
    gemm_bt<0><<<dim3(32, 32), t256, 0, stream>>>(h_bf, 4096, wbuf, 4096,
                                                  qkvp[i], 4096, nullptr, 4096);
  }
  // 5. RoPE + scale q by 1/sqrt(HD)
  rope_scale<<<32768, t256, 0, stream>>>(qbuf, kbuf, pos);
  // 6. V transpose to [B,NH,HD,S]
  vtrans<<<dim3(64, 8, 32), t32x8, 0, stream>>>(vbuf, vtb);
  // 7. attention -> ctx (bf16)
  attn_fwd<<<dim3(32, 32), t256, 0, stream>>>(qbuf, kbuf, vtb, amask, ctxb);
  // 8. out += ctx @ wo
  cvt_t<<<dim3(128, 128), t32x8, 0, stream>>>(wo, 4096, wbuf, 4096);
  gemm_bt<2><<<dim3(32, 32), t256, 0, stream>>>(ctxb, 4096, wbuf, 4096, out,
                                                4096, nullptr, 4096);
}

// Round 2
// 2288.869 us; speedup vs baseline: 1.4375x; 1.4375x over previous
//
#include <hip/hip_runtime.h>
#include <hip/hip_bf16.h>
#include <math.h>

namespace {

constexpr int kB = 2;
constexpr int kS = 2048;
constexpr int kH = 4096;
constexpr int kNH = 16;
constexpr int kHD = 256;

typedef __attribute__((ext_vector_type(4))) float f32x4;
typedef __attribute__((ext_vector_type(8))) short bf16x8;

__device__ __forceinline__ unsigned short f2bf(float f) {
  unsigned int u = __float_as_uint(f);
  u += 0x7FFFu + ((u >> 16) & 1u);
  return (unsigned short)(u >> 16);
}
__device__ __forceinline__ float bf2f(unsigned short h) {
  return __uint_as_float(((unsigned int)h) << 16);
}
__device__ __forceinline__ void gl2lds16(const void* g, void* l) {
  __builtin_amdgcn_global_load_lds(
      (const __attribute__((address_space(1))) unsigned int*)g,
      (__attribute__((address_space(3))) unsigned int*)l, 16, 0, 0);
}

// ---------------- LayerNorm: x -> h(bf16), out = x (residual init) ---------
__global__ __launch_bounds__(256) void ln_fwd(
    const float* __restrict__ x, const float* __restrict__ gam,
    const float* __restrict__ bet, unsigned short* __restrict__ hout,
    float* __restrict__ outp) {
  int row = blockIdx.x;
  int t = threadIdx.x;
  const float4* xr = (const float4*)(x + (size_t)row * kH);
  float4 v[4];
  float sum = 0.f, sq = 0.f;
#pragma unroll
  for (int i = 0; i < 4; i++) {
    v[i] = xr[t + i * 256];
    sum += v[i].x + v[i].y + v[i].z + v[i].w;
    sq += v[i].x * v[i].x + v[i].y * v[i].y + v[i].z * v[i].z + v[i].w * v[i].w;
  }
#pragma unroll
  for (int o = 32; o > 0; o >>= 1) {
    sum += __shfl_xor(sum, o);
    sq += __shfl_xor(sq, o);
  }
  __shared__ float red[8];
  if ((t & 63) == 0) { red[t >> 6] = sum; red[4 + (t >> 6)] = sq; }
  __syncthreads();
  sum = red[0] + red[1] + red[2] + red[3];
  sq = red[4] + red[5] + red[6] + red[7];
  float mu = sum * (1.f / kH);
  float rstd = rsqrtf(sq * (1.f / kH) - mu * mu + 1e-5f);
  const float4* gp = (const float4*)gam;
  const float4* bp = (const float4*)bet;
  ushort4* hr = (ushort4*)(hout + (size_t)row * kH);
  float4* orow = (float4*)(outp + (size_t)row * kH);
#pragma unroll
  for (int i = 0; i < 4; i++) {
    float4 g = gp[t + i * 256];
    float4 bb = bp[t + i * 256];
    ushort4 hv;
    hv.x = f2bf((v[i].x - mu) * rstd * g.x + bb.x);
    hv.y = f2bf((v[i].y - mu) * rstd * g.y + bb.y);
    hv.z = f2bf((v[i].z - mu) * rstd * g.z + bb.z);
    hv.w = f2bf((v[i].w - mu) * rstd * g.w + bb.w);
    hr[t + i * 256] = hv;
    orow[t + i * 256] = v[i];
  }
}

// ------- transpose-convert: out[n][k] = bf16(in[k][n]) ---------------------
__global__ __launch_bounds__(256) void cvt_t(
    const float* __restrict__ in, int ldin, unsigned short* __restrict__ outp,
    int ldout) {
  __shared__ float tile[32][33];
  int n0 = blockIdx.x * 32, k0 = blockIdx.y * 32;
  int tx = threadIdx.x, ty = threadIdx.y;
#pragma unroll
  for (int i = 0; i < 4; i++)
    tile[ty + i * 8][tx] = in[(size_t)(k0 + ty + i * 8) * ldin + n0 + tx];
  __syncthreads();
#pragma unroll
  for (int i = 0; i < 4; i++)
    outp[(size_t)(n0 + ty + i * 8) * ldout + k0 + tx] =
        f2bf(tile[tx][ty + i * 8]);
}

// ------- v [B,S,NH,HD] -> vt [B,NH,HD,S] (bf16) ----------------------------
__global__ __launch_bounds__(256) void vtrans(
    const unsigned short* __restrict__ v, unsigned short* __restrict__ vt) {
  __shared__ unsigned short tile[32][33];
  int bh = blockIdx.z;
  int s0 = blockIdx.x * 32, d0 = blockIdx.y * 32;
  int tx = threadIdx.x, ty = threadIdx.y;
  int b = bh >> 4, h = bh & 15;
  const unsigned short* src = v + (size_t)(b * kS) * kH + h * kHD;
#pragma unroll
  for (int i = 0; i < 4; i++)
    tile[ty + i * 8][tx] = src[(size_t)(s0 + ty + i * 8) * kH + d0 + tx];
  __syncthreads();
  unsigned short* dst = vt + (size_t)bh * kHD * kS;
#pragma unroll
  for (int i = 0; i < 4; i++)
    dst[(size_t)(d0 + ty + i * 8) * kS + s0 + tx] = tile[tx][ty + i * 8];
}

// ------- RoPE (pairs) + q-scale 1/16, in place -----------------------------
__global__ __launch_bounds__(256) void rope_scale(
    unsigned short* __restrict__ q, unsigned short* __restrict__ k,
    const int* __restrict__ pos) {
  int idx = blockIdx.x * 256 + threadIdx.x;  // pair index over B*S*NH*(HD/2)
  int j = idx & 127;
  int rowh = idx >> 7;  // b*S*NH + s*NH + h
  int h = rowh & 15;
  int s = (rowh >> 4) & 2047;
  int b = rowh >> 15;
  size_t off = ((size_t)(b * kS + s)) * kH + h * kHD + 2 * j;
  const float SCALE = 0.0625f;  // 1/sqrt(256)
  if (j < 32) {
    int p = pos[b * kS + s];
    float inv = exp2f(-(float)j * (13.287712379549449f / 32.f));  // 10000^(-j/32)
    float fr = (float)p * inv;
    float sn, cs;
    sincosf(fr, &sn, &cs);
    float e = bf2f(q[off]), o = bf2f(q[off + 1]);
    q[off] = f2bf((e * cs - o * sn) * SCALE);
    q[off + 1] = f2bf((o * cs + e * sn) * SCALE);
    e = bf2f(k[off]); o = bf2f(k[off + 1]);
    k[off] = f2bf(e * cs - o * sn);
    k[off + 1] = f2bf(o * cs + e * sn);
  } else {
    q[off] = f2bf(bf2f(q[off]) * SCALE);
    q[off + 1] = f2bf(bf2f(q[off + 1]) * SCALE);
  }
}

// ======= 256x256 8-phase deep-pipelined GEMM, BK=64, 8 waves ===============
// C[M][N] = A[M][K] * Bt[N][K]^T.
// EPI 0: bf16 store. 1: bf16(gelu(v+bias[n])). 2: Cf[idx]+=v. 3: +=v+bias[n].
//
// LDS buffer (64KB x 2): A at +0 (AE: rows 0-63 @0, 128-191 @8K;
//                               AL: rows 64-127 @16K, 192-255 @24K)
//                        B at +32768 (rows 0-255, linear 128B rows)
// 3-bit XOR chunk swizzle (chunk ^= row&7), inverse-applied on global src.
// Per tile: stage {p0:Bh0, p1:Bh1, p2:AE, p3:AL} of tile t+1 (2 gl2lds each);
// waits: vmcnt(4) @p1-end (forces AL_t), vmcnt(2)+lgkmcnt(0) @boundary
// (forces B/AE of t+1; AL_{t+1} stays in flight).
#define AF_MMA(P)                                                           \
  {                                                                         \
    bf16x8 af_[2][2];                                                       \
    _Pragma("unroll") for (int fm = 0; fm < 2; fm++)                        \
        _Pragma("unroll") for (int kk = 0; kk < 2; kk++) {                  \
      int q_ = (2 * (P) + fm) * 16 + l15;                                   \
      af_[fm][kk] = *(const bf16x8*)(cur + ((q_ & 64) << 8) + wm * 8192 +   \
                                     ((q_ & 63) << 7) +                     \
                                     ((((kk << 2) | l4) ^ key) << 4));      \
    }                                                                       \
    asm volatile("s_barrier" ::: "memory");                                 \
    __builtin_amdgcn_s_setprio(1);                                          \
    _Pragma("unroll") for (int fm = 0; fm < 2; fm++)                        \
        _Pragma("unroll") for (int fn = 0; fn < 4; fn++)                    \
            _Pragma("unroll") for (int kk = 0; kk < 2; kk++)                \
      acc[2 * (P) + fm][fn] = __builtin_amdgcn_mfma_f32_16x16x32_bf16(      \
          af_[fm][kk], bfr[fn][kk], acc[2 * (P) + fm][fn], 0, 0, 0);        \
    __builtin_amdgcn_s_setprio(0);                                          \
  }

template <int EPI>
__global__ __launch_bounds__(512, 2) void gemm256(
    const unsigned short* __restrict__ A, int lda,
    const unsigned short* __restrict__ Bt, int ldb, void* __restrict__ Cp,
    int ldc, const float* __restrict__ bias, int K, int gx) {
  __shared__ __align__(16) char lds[131072];
  const int t = threadIdx.x;
  const int lane = t & 63, w = t >> 6;
  const int wm = w >> 2, wn = w & 3;
  const int l15 = lane & 15, l4 = lane >> 4;
  const int key = l15 & 7;

  const int nwg = gridDim.x;
  const int orig = blockIdx.x;
  const int wg = (orig & 7) * (nwg >> 3) + (orig >> 3);  // XCD swizzle (nwg%8==0)
  const int bx = wg % gx, by = wg / gx;
  const int m0 = by * 256, n0 = bx * 256;

  // staging source pointers (inverse-swizzled chunk)
  const int lr = t >> 3, ch = t & 7;
  const int swk = (ch ^ (lr & 7)) * 8;
  const unsigned short* aE0 = A + (size_t)(m0 + lr) * lda + swk;
  const unsigned short* aE1 = A + (size_t)(m0 + 128 + lr) * lda + swk;
  const unsigned short* aL0 = A + (size_t)(m0 + 64 + lr) * lda + swk;
  const unsigned short* aL1 = A + (size_t)(m0 + 192 + lr) * lda + swk;
  const unsigned short* b00 = Bt + (size_t)(n0 + lr) * ldb + swk;
  const unsigned short* b01 = Bt + (size_t)(n0 + 64 + lr) * ldb + swk;
  const unsigned short* b10 = Bt + (size_t)(n0 + 128 + lr) * ldb + swk;
  const unsigned short* b11 = Bt + (size_t)(n0 + 192 + lr) * ldb + swk;
  const int t16 = t * 16;

  f32x4 acc[8][4];
#pragma unroll
  for (int m = 0; m < 8; m++)
#pragma unroll
    for (int n = 0; n < 4; n++) acc[m][n] = (f32x4)(0.f);

  // prologue: stage tile 0 fully into buffer 0
  {
    char* b = lds;
    gl2lds16(b00, b + 32768 + t16); b00 += 64;
    gl2lds16(b01, b + 40960 + t16); b01 += 64;
    gl2lds16(b10, b + 49152 + t16); b10 += 64;
    gl2lds16(b11, b + 57344 + t16); b11 += 64;
    gl2lds16(aE0, b + t16);         aE0 += 64;
    gl2lds16(aE1, b + 8192 + t16);  aE1 += 64;
    gl2lds16(aL0, b + 16384 + t16); aL0 += 64;
    gl2lds16(aL1, b + 24576 + t16); aL1 += 64;
  }
  asm volatile("s_waitcnt vmcnt(0)" ::: "memory");
  asm volatile("s_barrier" ::: "memory");

  const int nt = K >> 6;
  for (int kt = 0; kt < nt; ++kt) {
    const char* cur = lds + (kt & 1) * 65536;
    char* nxt = lds + (((kt & 1) ^ 1)) * 65536;
    const bool pre = (kt + 1 < nt);
    bf16x8 bfr[4][2];
    // ---- phase 0: stage Bh0(t+1); read all B frags + A(p0); MFMA quad 0
    if (pre) {
      gl2lds16(b00, nxt + 32768 + t16); b00 += 64;
      gl2lds16(b01, nxt + 40960 + t16); b01 += 64;
    }
#pragma unroll
    for (int fn = 0; fn < 4; fn++)
#pragma unroll
      for (int kk = 0; kk < 2; kk++) {
        int n = wn * 64 + fn * 16 + l15;
        bfr[fn][kk] = *(const bf16x8*)(cur + 32768 + (n << 7) +
                                       ((((kk << 2) | l4) ^ key) << 4));
      }
    AF_MMA(0)
    asm volatile("s_barrier" ::: "memory");
    // ---- phase 1: stage Bh1(t+1); MFMA quad 1; vmcnt(4) forces AL_t
    if (pre) {
      gl2lds16(b10, nxt + 49152 + t16); b10 += 64;
      gl2lds16(b11, nxt + 57344 + t16); b11 += 64;
    }
    AF_MMA(1)
    if (pre) asm volatile("s_waitcnt vmcnt(4)" ::: "memory");
    else     asm volatile("s_waitcnt vmcnt(0)" ::: "memory");
    asm volatile("s_barrier" ::: "memory");
    // ---- phase 2: stage AE(t+1); MFMA quad 2
    if (pre) {
      gl2lds16(aE0, nxt + t16);        aE0 += 64;
      gl2lds16(aE1, nxt + 8192 + t16); aE1 += 64;
    }
    AF_MMA(2)
    asm volatile("s_barrier" ::: "memory");
    // ---- phase 3: stage AL(t+1); MFMA quad 3; boundary wait
    if (pre) {
      gl2lds16(aL0, nxt + 16384 + t16); aL0 += 64;
      gl2lds16(aL1, nxt + 24576 + t16); aL1 += 64;
    }
    AF_MMA(3)
    asm volatile("s_waitcnt lgkmcnt(0)" ::: "memory");
    if (pre) asm volatile("s_waitcnt vmcnt(2)" ::: "memory");
    asm volatile("s_barrier" ::: "memory");
  }

  // epilogue
  const int crow = m0 + wm * 128 + l4 * 4;
  const int ccol = n0 + wn * 64 + l15;
#pragma unroll
  for (int m = 0; m < 8; m++) {
#pragma unroll
    for (int n = 0; n < 4; n++) {
      int col = ccol + n * 16;
#pragma unroll
      for (int r = 0; r < 4; r++) {
        int row = crow + m * 16 + r;
        float v = acc[m][n][r];
        size_t idx = (size_t)row * ldc + col;
        if constexpr (EPI == 0) {
          ((unsigned short*)Cp)[idx] = f2bf(v);
        } else if constexpr (EPI == 1) {
          float u = v + bias[col];
          float c = 0.7978845608028654f * (u + 0.044715f * u * u * u);
          float g = u / (1.0f + __expf(-2.0f * c));  // u*0.5*(1+tanh(c))
          ((unsigned short*)Cp)[idx] = f2bf(g);
        } else if constexpr (EPI == 2) {
          ((float*)Cp)[idx] += v;
        } else {
          ((float*)Cp)[idx] += v + bias[col];
        }
      }
    }
  }
}

// ------- flash attention: 4 waves x 16 q-rows, KVBLK=32, HD=256 ------------
__global__ __launch_bounds__(256) void attn_fwd(
    const unsigned short* __restrict__ q, const unsigned short* __restrict__ k,
    const unsigned short* __restrict__ vt, const int* __restrict__ amask,
    unsigned short* __restrict__ ctx) {
  __shared__ unsigned short sK[32 * 256];   // [kv][d], 512B rows, swz row&7
  __shared__ unsigned short sV[256 * 32];   // [d][kv], 64B rows, swz (row>>1)&3
  __shared__ unsigned short sP[4 * 16 * 32];  // per-wave P, 64B rows
  int t = threadIdx.x, lane = t & 63, w = t >> 6;
  int qb = blockIdx.x, bh = blockIdx.y;
  int b = bh >> 4, h = bh & 15;
  int l15 = lane & 15, l4 = lane >> 4;

  bf16x8 qf[8];
  {
    int qrow = qb * 64 + w * 16 + l15;
    const unsigned short* qp =
        q + (size_t)(b * kS + qrow) * kH + h * kHD + l4 * 8;
#pragma unroll
    for (int ks = 0; ks < 8; ks++) qf[ks] = *(const bf16x8*)(qp + ks * 32);
  }
  f32x4 o[16];
#pragma unroll
  for (int nf = 0; nf < 16; nf++) o[nf] = (f32x4)(0.f);
  float mr[4] = {-INFINITY, -INFINITY, -INFINITY, -INFINITY};
  float lr[4] = {0.f, 0.f, 0.f, 0.f};

  int krow = t >> 5, kchk = t & 31;  // K tile staging
  int vrow = t >> 2, vchk = t & 3;   // V tile staging
  const unsigned short* kbase = k + (size_t)(b * kS) * kH + h * kHD;
  const unsigned short* vbase = vt + (size_t)bh * kHD * kS;
  int ntiles = 2 * qb + 2;

  for (int kvt = 0; kvt < ntiles; kvt++) {
    int kv0 = kvt * 32;
    __syncthreads();
#pragma unroll
    for (int i = 0; i < 4; i++) {
      int row = krow + i * 8;
      int csw = kchk ^ (row & 7);
      gl2lds16(kbase + (size_t)(kv0 + row) * kH + csw * 8,
               (char*)sK + i * 4096 + t * 16);
      int d = vrow + i * 64;
      int csw2 = vchk ^ ((d >> 1) & 3);
      gl2lds16(vbase + (size_t)d * kS + kv0 + csw2 * 8,
               (char*)sV + i * 4096 + t * 16);
    }
    __syncthreads();

    f32x4 sc[2];
    sc[0] = (f32x4)(0.f);
    sc[1] = (f32x4)(0.f);
#pragma unroll
    for (int nf = 0; nf < 2; nf++) {
      int row = nf * 16 + l15;
#pragma unroll
      for (int ks = 0; ks < 8; ks++) {
        int slot = (ks * 4 + l4) ^ (row & 7);
        bf16x8 kf = *(const bf16x8*)&sK[row * 256 + slot * 8];
        sc[nf] = __builtin_amdgcn_mfma_f32_16x16x32_bf16(qf[ks], kf, sc[nf], 0, 0, 0);
      }
    }

    int am0 = amask[b * kS + kv0 + l15];
    int am1 = amask[b * kS + kv0 + 16 + l15];
    int kva = kv0 + l15, kvb = kv0 + 16 + l15;
#pragma unroll
    for (int r = 0; r < 4; r++) {
      int qi = qb * 64 + w * 16 + l4 * 4 + r;
      float s0v = (kva <= qi && am0 != 0) ? sc[0][r] : -INFINITY;
      float s1v = (kvb <= qi && am1 != 0) ? sc[1][r] : -INFINITY;
      float mx = fmaxf(s0v, s1v);
#pragma unroll
      for (int d = 1; d < 16; d <<= 1) mx = fmaxf(mx, __shfl_xor(mx, d));
      float mn = fmaxf(mr[r], mx);
      float corr = __expf(mr[r] - mn);
      float p0 = __expf(s0v - mn);
      float p1 = __expf(s1v - mn);
      float rsum = p0 + p1;
#pragma unroll
      for (int d = 1; d < 16; d <<= 1) rsum += __shfl_xor(rsum, d);
      lr[r] = lr[r] * corr + rsum;
      mr[r] = mn;
#pragma unroll
      for (int nf = 0; nf < 16; nf++) o[nf][r] *= corr;
      int prow = l4 * 4 + r;
      int swz = ((prow >> 1) & 3) << 4;
      int byte0 = prow * 64 + ((l15 * 2) ^ swz);
      int byte1 = prow * 64 + (((16 + l15) * 2) ^ swz);
      sP[w * 512 + (byte0 >> 1)] = f2bf(p0);
      sP[w * 512 + (byte1 >> 1)] = f2bf(p1);
    }

    // PV
    int pslot = l4 ^ ((l15 >> 1) & 3);
    bf16x8 pa = *(const bf16x8*)&sP[w * 512 + l15 * 32 + pslot * 8];
#pragma unroll
    for (int nf = 0; nf < 16; nf++) {
      int vr = nf * 16 + l15;
      int vslot = l4 ^ ((vr >> 1) & 3);
      bf16x8 vf = *(const bf16x8*)&sV[vr * 32 + vslot * 8];
      o[nf] = __builtin_amdgcn_mfma_f32_16x16x32_bf16(pa, vf, o[nf], 0, 0, 0);
    }
  }

  float invl[4];
#pragma unroll
  for (int r = 0; r < 4; r++) invl[r] = 1.0f / lr[r];
#pragma unroll
  for (int nf = 0; nf < 16; nf++) {
    int d = nf * 16 + l15;
#pragma unroll
    for (int r = 0; r < 4; r++) {
      int qi = qb * 64 + w * 16 + l4 * 4 + r;
      ctx[(size_t)(b * kS + qi) * kH + h * kHD + d] = f2bf(o[nf][r] * invl[r]);
    }
  }
}

}  // namespace

extern "C" void kernel_launch(void* const* d_in, const int* in_sizes, int n_in,
                              void* d_out, int out_size, void* d_ws,
                              size_t ws_size, hipStream_t stream) {
  const float* x = (const float*)d_in[0];
  const int* amask = (const int*)d_in[1];
  const int* pos = (const int*)d_in[2];
  const float* lns = (const float*)d_in[3];
  const float* lnb = (const float*)d_in[4];
  const float* wq = (const float*)d_in[5];
  const float* wk = (const float*)d_in[6];
  const float* wv = (const float*)d_in[7];
  const float* wo = (const float*)d_in[8];
  const float* w_in = (const float*)d_in[9];
  const float* b_in = (const float*)d_in[10];
  const float* w_out = (const float*)d_in[11];
  const float* b_out = (const float*)d_in[12];
  float* out = (float*)d_out;

  if (ws_size < 268435456ull) return;  // need 256 MiB scratch
  char* ws = (char*)d_ws;
  unsigned short* h_bf = (unsigned short*)ws;                  // 32 MiB
  unsigned short* big = (unsigned short*)(ws + 33554432ull);   // 128 MiB
  unsigned short* vbuf = (unsigned short*)(ws + 167772160ull); // 32 MiB
  unsigned short* wbuf = (unsigned short*)(ws + 201326592ull); // 64 MiB
  unsigned short* mid = big;                    // [4096][16384] during MLP
  unsigned short* qbuf = big;                   // then q
  unsigned short* kbuf = big + 16777216;        // k
  unsigned short* vtb = big + 33554432;         // v^T [B,NH,HD,S]
  unsigned short* ctxb = vbuf;                  // ctx overwrites v after vtrans

  dim3 t256(256);
  dim3 t512(512);
  dim3 t32x8(32, 8);

  // 1. LayerNorm -> h (bf16); out = x
  ln_fwd<<<kB * kS, t256, 0, stream>>>(x, lns, lnb, h_bf, out);

  // 2. MLP first GEMM (two N-halves): mid = gelu(h @ w_in + b_in)
  for (int c = 0; c < 2; c++) {
    cvt_t<<<dim3(256, 128), t32x8, 0, stream>>>(w_in + c * 8192, 16384, wbuf, 4096);
    gemm256<1><<<dim3(512), t512, 0, stream>>>(
        h_bf, 4096, wbuf, 4096, mid + c * 8192, 16384, b_in + c * 8192, 4096, 32);
  }
  // 3. MLP second GEMM (two K-halves): out += mid @ w_out + b_out
  for (int c = 0; c < 2; c++) {
    cvt_t<<<dim3(128, 256), t32x8, 0, stream>>>(
        w_out + (size_t)c * 8192 * 4096, 4096, wbuf, 8192);
    if (c == 0)
      gemm256<3><<<dim3(256), t512, 0, stream>>>(mid + c * 8192, 16384, wbuf,
                                                 8192, out, 4096, b_out, 8192, 16);
    else
      gemm256<2><<<dim3(256), t512, 0, stream>>>(
          mid + c * 8192, 16384, wbuf, 8192, out, 4096, nullptr, 8192, 16);
  }

  // 4. QKV projections (mid region is free now; q,k go there, v separate)
  const float* wqkv[3] = {wq, wk, wv};
  unsigned short* qkvp[3] = {qbuf, kbuf, vbuf};
  for (int i = 0; i < 3; i++) {
    cvt_t<<<dim3(128, 128), t32x8, 0, stream>>>(wqkv[i], 4096, wbuf, 4096);
    gemm256<0><<<dim3(256), t512, 0, stream>>>(h_bf, 4096, wbuf, 4096,
                                               qkvp[i], 4096, nullptr, 4096, 16);
  }
  // 5. RoPE + scale q by 1/sqrt(HD)
  rope_scale<<<32768, t256, 0, stream>>>(qbuf, kbuf, pos);
  // 6. V transpose to [B,NH,HD,S]
  vtrans<<<dim3(64, 8, 32), t32x8, 0, stream>>>(vbuf, vtb);
  // 7. attention -> ctx (bf16)
  attn_fwd<<<dim3(32, 32), t256, 0, stream>>>(qbuf, kbuf, vtb, amask, ctxb);
  // 8. out += ctx @ wo
  cvt_t<<<dim3(128, 128), t32x8, 0, stream>>>(wo, 4096, wbuf, 4096);
  gemm256<2><<<dim3(256), t512, 0, stream>>>(ctxb, 4096, wbuf, 4096, out,
                                             4096, nullptr, 4096, 16);
}

// Round 3
// 2079.908 us; speedup vs baseline: 1.5819x; 1.1005x over previous
//
#include <hip/hip_runtime.h>
#include <hip/hip_bf16.h>
#include <math.h>

namespace {

constexpr int kB = 2;
constexpr int kS = 2048;
constexpr int kH = 4096;
constexpr int kNH = 16;
constexpr int kHD = 256;

typedef __attribute__((ext_vector_type(4))) float f32x4;
typedef __attribute__((ext_vector_type(8))) short bf16x8;

__device__ __forceinline__ unsigned short f2bf(float f) {
  unsigned int u = __float_as_uint(f);
  u += 0x7FFFu + ((u >> 16) & 1u);
  return (unsigned short)(u >> 16);
}
__device__ __forceinline__ float bf2f(unsigned short h) {
  return __uint_as_float(((unsigned int)h) << 16);
}
__device__ __forceinline__ void gl2lds16(const void* g, void* l) {
  __builtin_amdgcn_global_load_lds(
      (const __attribute__((address_space(1))) unsigned int*)g,
      (__attribute__((address_space(3))) unsigned int*)l, 16, 0, 0);
}

// ---------------- LayerNorm: x -> h(bf16), out = x (residual init) ---------
__global__ __launch_bounds__(256) void ln_fwd(
    const float* __restrict__ x, const float* __restrict__ gam,
    const float* __restrict__ bet, unsigned short* __restrict__ hout,
    float* __restrict__ outp) {
  int row = blockIdx.x;
  int t = threadIdx.x;
  const float4* xr = (const float4*)(x + (size_t)row * kH);
  float4 v[4];
  float sum = 0.f, sq = 0.f;
#pragma unroll
  for (int i = 0; i < 4; i++) {
    v[i] = xr[t + i * 256];
    sum += v[i].x + v[i].y + v[i].z + v[i].w;
    sq += v[i].x * v[i].x + v[i].y * v[i].y + v[i].z * v[i].z + v[i].w * v[i].w;
  }
#pragma unroll
  for (int o = 32; o > 0; o >>= 1) {
    sum += __shfl_xor(sum, o);
    sq += __shfl_xor(sq, o);
  }
  __shared__ float red[8];
  if ((t & 63) == 0) { red[t >> 6] = sum; red[4 + (t >> 6)] = sq; }
  __syncthreads();
  sum = red[0] + red[1] + red[2] + red[3];
  sq = red[4] + red[5] + red[6] + red[7];
  float mu = sum * (1.f / kH);
  float rstd = rsqrtf(sq * (1.f / kH) - mu * mu + 1e-5f);
  const float4* gp = (const float4*)gam;
  const float4* bp = (const float4*)bet;
  ushort4* hr = (ushort4*)(hout + (size_t)row * kH);
  float4* orow = (float4*)(outp + (size_t)row * kH);
#pragma unroll
  for (int i = 0; i < 4; i++) {
    float4 g = gp[t + i * 256];
    float4 bb = bp[t + i * 256];
    ushort4 hv;
    hv.x = f2bf((v[i].x - mu) * rstd * g.x + bb.x);
    hv.y = f2bf((v[i].y - mu) * rstd * g.y + bb.y);
    hv.z = f2bf((v[i].z - mu) * rstd * g.z + bb.z);
    hv.w = f2bf((v[i].w - mu) * rstd * g.w + bb.w);
    hr[t + i * 256] = hv;
    orow[t + i * 256] = v[i];
  }
}

// ------- transpose-convert: out[n][k] = bf16(in[k][n]) ---------------------
__global__ __launch_bounds__(256) void cvt_t(
    const float* __restrict__ in, int ldin, unsigned short* __restrict__ outp,
    int ldout) {
  __shared__ float tile[32][33];
  int n0 = blockIdx.x * 32, k0 = blockIdx.y * 32;
  int tx = threadIdx.x, ty = threadIdx.y;
#pragma unroll
  for (int i = 0; i < 4; i++)
    tile[ty + i * 8][tx] = in[(size_t)(k0 + ty + i * 8) * ldin + n0 + tx];
  __syncthreads();
#pragma unroll
  for (int i = 0; i < 4; i++)
    outp[(size_t)(n0 + ty + i * 8) * ldout + k0 + tx] =
        f2bf(tile[tx][ty + i * 8]);
}

// ------- v [B,S,NH,HD] -> vt [B,NH,HD,S] (bf16) ----------------------------
__global__ __launch_bounds__(256) void vtrans(
    const unsigned short* __restrict__ v, unsigned short* __restrict__ vt) {
  __shared__ unsigned short tile[32][33];
  int bh = blockIdx.z;
  int s0 = blockIdx.x * 32, d0 = blockIdx.y * 32;
  int tx = threadIdx.x, ty = threadIdx.y;
  int b = bh >> 4, h = bh & 15;
  const unsigned short* src = v + (size_t)(b * kS) * kH + h * kHD;
#pragma unroll
  for (int i = 0; i < 4; i++)
    tile[ty + i * 8][tx] = src[(size_t)(s0 + ty + i * 8) * kH + d0 + tx];
  __syncthreads();
  unsigned short* dst = vt + (size_t)bh * kHD * kS;
#pragma unroll
  for (int i = 0; i < 4; i++)
    dst[(size_t)(d0 + ty + i * 8) * kS + s0 + tx] = tile[tx][ty + i * 8];
}

// ------- RoPE (pairs) + q-scale 1/16, in place -----------------------------
__global__ __launch_bounds__(256) void rope_scale(
    unsigned short* __restrict__ q, unsigned short* __restrict__ k,
    const int* __restrict__ pos) {
  int idx = blockIdx.x * 256 + threadIdx.x;  // pair index over B*S*NH*(HD/2)
  int j = idx & 127;
  int rowh = idx >> 7;  // b*S*NH + s*NH + h
  int h = rowh & 15;
  int s = (rowh >> 4) & 2047;
  int b = rowh >> 15;
  size_t off = ((size_t)(b * kS + s)) * kH + h * kHD + 2 * j;
  const float SCALE = 0.0625f;  // 1/sqrt(256)
  if (j < 32) {
    int p = pos[b * kS + s];
    float inv = exp2f(-(float)j * (13.287712379549449f / 32.f));  // 10000^(-j/32)
    float fr = (float)p * inv;
    float sn, cs;
    sincosf(fr, &sn, &cs);
    float e = bf2f(q[off]), o = bf2f(q[off + 1]);
    q[off] = f2bf((e * cs - o * sn) * SCALE);
    q[off + 1] = f2bf((o * cs + e * sn) * SCALE);
    e = bf2f(k[off]); o = bf2f(k[off + 1]);
    k[off] = f2bf(e * cs - o * sn);
    k[off + 1] = f2bf(o * cs + e * sn);
  } else {
    q[off] = f2bf(bf2f(q[off]) * SCALE);
    q[off + 1] = f2bf(bf2f(q[off + 1]) * SCALE);
  }
}

// ======= 256x256 8-phase deep-pipelined GEMM, BK=64, 8 waves ===============
#define AF_MMA(P)                                                           \
  {                                                                         \
    bf16x8 af_[2][2];                                                       \
    _Pragma("unroll") for (int fm = 0; fm < 2; fm++)                        \
        _Pragma("unroll") for (int kk = 0; kk < 2; kk++) {                  \
      int q_ = (2 * (P) + fm) * 16 + l15;                                   \
      af_[fm][kk] = *(const bf16x8*)(cur + ((q_ & 64) << 8) + wm * 8192 +   \
                                     ((q_ & 63) << 7) +                     \
                                     ((((kk << 2) | l4) ^ key) << 4));      \
    }                                                                       \
    asm volatile("s_barrier" ::: "memory");                                 \
    __builtin_amdgcn_s_setprio(1);                                          \
    _Pragma("unroll") for (int fm = 0; fm < 2; fm++)                        \
        _Pragma("unroll") for (int fn = 0; fn < 4; fn++)                    \
            _Pragma("unroll") for (int kk = 0; kk < 2; kk++)                \
      acc[2 * (P) + fm][fn] = __builtin_amdgcn_mfma_f32_16x16x32_bf16(      \
          af_[fm][kk], bfr[fn][kk], acc[2 * (P) + fm][fn], 0, 0, 0);        \
    __builtin_amdgcn_s_setprio(0);                                          \
  }

template <int EPI>
__global__ __launch_bounds__(512, 2) void gemm256(
    const unsigned short* __restrict__ A, int lda,
    const unsigned short* __restrict__ Bt, int ldb, void* __restrict__ Cp,
    int ldc, const float* __restrict__ bias, int K, int gx) {
  __shared__ __align__(16) char lds[131072];
  const int t = threadIdx.x;
  const int lane = t & 63, w = t >> 6;
  const int wm = w >> 2, wn = w & 3;
  const int l15 = lane & 15, l4 = lane >> 4;
  const int key = l15 & 7;

  const int nwg = gridDim.x;
  const int orig = blockIdx.x;
  const int wg = (orig & 7) * (nwg >> 3) + (orig >> 3);  // XCD swizzle (nwg%8==0)
  const int bx = wg % gx, by = wg / gx;
  const int m0 = by * 256, n0 = bx * 256;

  const int lr = t >> 3, ch = t & 7;
  const int swk = (ch ^ (lr & 7)) * 8;
  const unsigned short* aE0 = A + (size_t)(m0 + lr) * lda + swk;
  const unsigned short* aE1 = A + (size_t)(m0 + 128 + lr) * lda + swk;
  const unsigned short* aL0 = A + (size_t)(m0 + 64 + lr) * lda + swk;
  const unsigned short* aL1 = A + (size_t)(m0 + 192 + lr) * lda + swk;
  const unsigned short* b00 = Bt + (size_t)(n0 + lr) * ldb + swk;
  const unsigned short* b01 = Bt + (size_t)(n0 + 64 + lr) * ldb + swk;
  const unsigned short* b10 = Bt + (size_t)(n0 + 128 + lr) * ldb + swk;
  const unsigned short* b11 = Bt + (size_t)(n0 + 192 + lr) * ldb + swk;
  const int t16 = t * 16;

  f32x4 acc[8][4];
#pragma unroll
  for (int m = 0; m < 8; m++)
#pragma unroll
    for (int n = 0; n < 4; n++) acc[m][n] = (f32x4)(0.f);

  {
    char* b = lds;
    gl2lds16(b00, b + 32768 + t16); b00 += 64;
    gl2lds16(b01, b + 40960 + t16); b01 += 64;
    gl2lds16(b10, b + 49152 + t16); b10 += 64;
    gl2lds16(b11, b + 57344 + t16); b11 += 64;
    gl2lds16(aE0, b + t16);         aE0 += 64;
    gl2lds16(aE1, b + 8192 + t16);  aE1 += 64;
    gl2lds16(aL0, b + 16384 + t16); aL0 += 64;
    gl2lds16(aL1, b + 24576 + t16); aL1 += 64;
  }
  asm volatile("s_waitcnt vmcnt(0)" ::: "memory");
  asm volatile("s_barrier" ::: "memory");

  const int nt = K >> 6;
  for (int kt = 0; kt < nt; ++kt) {
    const char* cur = lds + (kt & 1) * 65536;
    char* nxt = lds + (((kt & 1) ^ 1)) * 65536;
    const bool pre = (kt + 1 < nt);
    bf16x8 bfr[4][2];
    if (pre) {
      gl2lds16(b00, nxt + 32768 + t16); b00 += 64;
      gl2lds16(b01, nxt + 40960 + t16); b01 += 64;
    }
#pragma unroll
    for (int fn = 0; fn < 4; fn++)
#pragma unroll
      for (int kk = 0; kk < 2; kk++) {
        int n = wn * 64 + fn * 16 + l15;
        bfr[fn][kk] = *(const bf16x8*)(cur + 32768 + (n << 7) +
                                       ((((kk << 2) | l4) ^ key) << 4));
      }
    AF_MMA(0)
    asm volatile("s_barrier" ::: "memory");
    if (pre) {
      gl2lds16(b10, nxt + 49152 + t16); b10 += 64;
      gl2lds16(b11, nxt + 57344 + t16); b11 += 64;
    }
    AF_MMA(1)
    if (pre) asm volatile("s_waitcnt vmcnt(4)" ::: "memory");
    else     asm volatile("s_waitcnt vmcnt(0)" ::: "memory");
    asm volatile("s_barrier" ::: "memory");
    if (pre) {
      gl2lds16(aE0, nxt + t16);        aE0 += 64;
      gl2lds16(aE1, nxt + 8192 + t16); aE1 += 64;
    }
    AF_MMA(2)
    asm volatile("s_barrier" ::: "memory");
    if (pre) {
      gl2lds16(aL0, nxt + 16384 + t16); aL0 += 64;
      gl2lds16(aL1, nxt + 24576 + t16); aL1 += 64;
    }
    AF_MMA(3)
    asm volatile("s_waitcnt lgkmcnt(0)" ::: "memory");
    if (pre) asm volatile("s_waitcnt vmcnt(2)" ::: "memory");
    asm volatile("s_barrier" ::: "memory");
  }

  const int crow = m0 + wm * 128 + l4 * 4;
  const int ccol = n0 + wn * 64 + l15;
#pragma unroll
  for (int m = 0; m < 8; m++) {
#pragma unroll
    for (int n = 0; n < 4; n++) {
      int col = ccol + n * 16;
#pragma unroll
      for (int r = 0; r < 4; r++) {
        int row = crow + m * 16 + r;
        float v = acc[m][n][r];
        size_t idx = (size_t)row * ldc + col;
        if constexpr (EPI == 0) {
          ((unsigned short*)Cp)[idx] = f2bf(v);
        } else if constexpr (EPI == 1) {
          float u = v + bias[col];
          float c = 0.7978845608028654f * (u + 0.044715f * u * u * u);
          float g = u / (1.0f + __expf(-2.0f * c));
          ((unsigned short*)Cp)[idx] = f2bf(g);
        } else if constexpr (EPI == 2) {
          ((float*)Cp)[idx] += v;
        } else {
          ((float*)Cp)[idx] += v + bias[col];
        }
      }
    }
  }
}

// ======= flash attention v3: 8 waves, QBLK=128, KVBLK=64, pipelined ========
// LDS: K dbuf 2x[64][256] @0/32768, V dbuf 2x[256][64] @65536/98304,
//      P per-wave [16][64] @131072 + w*2048.  (144 KiB)
// Per tile: issue 8 gl2lds for t+1, vmcnt(8) (t resident), barrier,
// QK -> masked online softmax (defer-max THR=8) -> P(LDS) -> PV, barrier.
__global__ __launch_bounds__(512) void attn_fwd(
    const unsigned short* __restrict__ q, const unsigned short* __restrict__ k,
    const unsigned short* __restrict__ vt, const int* __restrict__ amask,
    unsigned short* __restrict__ ctx) {
  __shared__ __align__(16) char alds[147456];
  const int t = threadIdx.x, lane = t & 63, w = t >> 6;
  const int bid = blockIdx.x;
  const int qb = 15 - (bid >> 5);       // heavy-first
  const int bh = bid & 31;
  const int b = bh >> 4, h = bh & 15;
  const int l15 = lane & 15, l4 = lane >> 4;
  const int qbase = qb * 128;

  // Q fragments (16 q-rows per wave)
  bf16x8 qf[8];
  {
    int qrow = qbase + w * 16 + l15;
    const unsigned short* qp =
        q + (size_t)(b * kS + qrow) * kH + h * kHD + l4 * 8;
#pragma unroll
    for (int ks = 0; ks < 8; ks++) qf[ks] = *(const bf16x8*)(qp + ks * 32);
  }
  f32x4 o[16];
#pragma unroll
  for (int nf = 0; nf < 16; nf++) o[nf] = (f32x4)(0.f);
  float mr[4] = {-INFINITY, -INFINITY, -INFINITY, -INFINITY};
  float lr[4] = {0.f, 0.f, 0.f, 0.f};

  const unsigned short* kbase = k + (size_t)(b * kS) * kH + h * kHD;
  const unsigned short* vbase = vt + (size_t)bh * kHD * kS;
  unsigned short* sPw = (unsigned short*)(alds + 131072 + w * 2048);
  const int nt = 2 * qb + 2;

  // staging geometry (512 threads, 16B each, 4 passes per operand)
  const int krow = t >> 5, kch = t & 31;          // K: 16 rows/pass
  const int kcs = (kch ^ (krow & 7)) * 8;
  const int vrow = t >> 3, vch = t & 7;           // V: 64 rows/pass
  const int vcs = (vch ^ (vrow & 7)) * 8;
  const int t16b = t * 16;

#define ATTN_STAGE(KV0, BUF)                                                 \
  {                                                                          \
    char* kd = alds + (BUF) * 32768;                                         \
    char* vd = alds + 65536 + (BUF) * 32768;                                 \
    _Pragma("unroll") for (int i = 0; i < 4; i++) {                          \
      gl2lds16(kbase + (size_t)((KV0) + krow + i * 16) * kH + kcs,           \
               kd + i * 8192 + t16b);                                        \
      gl2lds16(vbase + (size_t)(vrow + i * 64) * kS + (KV0) + vcs,           \
               vd + i * 8192 + t16b);                                        \
    }                                                                        \
  }

  ATTN_STAGE(0, 0)

  for (int kvt = 0; kvt < nt; kvt++) {
    const int kv0 = kvt * 64;
    const int cb = kvt & 1;
    if (kvt + 1 < nt) {
      ATTN_STAGE(kv0 + 64, cb ^ 1)
      asm volatile("s_waitcnt vmcnt(8)" ::: "memory");
    } else {
      asm volatile("s_waitcnt vmcnt(0)" ::: "memory");
    }
    asm volatile("s_barrier" ::: "memory");

    const unsigned short* sK = (const unsigned short*)(alds + cb * 32768);
    const unsigned short* sV =
        (const unsigned short*)(alds + 65536 + cb * 32768);

    // QK^T
    f32x4 sc[4];
#pragma unroll
    for (int g = 0; g < 4; g++) sc[g] = (f32x4)(0.f);
    __builtin_amdgcn_s_setprio(1);
#pragma unroll
    for (int g = 0; g < 4; g++) {
      int row = g * 16 + l15;
#pragma unroll
      for (int ks = 0; ks < 8; ks++) {
        bf16x8 kf =
            *(const bf16x8*)&sK[row * 256 + (((ks * 4 + l4) ^ (row & 7)) * 8)];
        sc[g] = __builtin_amdgcn_mfma_f32_16x16x32_bf16(qf[ks], kf, sc[g], 0, 0, 0);
      }
    }
    __builtin_amdgcn_s_setprio(0);

    // mask + row max
    int am[4];
#pragma unroll
    for (int g = 0; g < 4; g++) am[g] = amask[b * kS + kv0 + g * 16 + l15];
    float mx[4];
#pragma unroll
    for (int r = 0; r < 4; r++) {
      int qi = qbase + w * 16 + l4 * 4 + r;
      float a = -INFINITY;
#pragma unroll
      for (int g = 0; g < 4; g++) {
        bool ok = (kv0 + g * 16 + l15 <= qi) && (am[g] != 0);
        float s = ok ? sc[g][r] : -INFINITY;
        sc[g][r] = s;
        a = fmaxf(a, s);
      }
#pragma unroll
      for (int d = 1; d < 16; d <<= 1) a = fmaxf(a, __shfl_xor(a, d));
      mx[r] = a;
    }
    // defer-max rescale
    bool nd = false;
#pragma unroll
    for (int r = 0; r < 4; r++) nd |= (mx[r] > mr[r] + 8.f);
    if (__any(nd)) {
#pragma unroll
      for (int r = 0; r < 4; r++) {
        float nm = fmaxf(mr[r], mx[r]);
        float c = __expf(mr[r] - nm);
        lr[r] *= c;
        mr[r] = nm;
#pragma unroll
        for (int nf = 0; nf < 16; nf++) o[nf][r] *= c;
      }
    }
    // P = exp(s - m), write to LDS (swizzled), accumulate l
#pragma unroll
    for (int r = 0; r < 4; r++) {
      int prow = l4 * 4 + r;
      int pkey = (prow ^ (prow >> 2)) & 7;
      float rs = 0.f;
#pragma unroll
      for (int g = 0; g < 4; g++) {
        float p = __expf(sc[g][r] - mr[r]);
        rs += p;
        int kvl = g * 16 + l15;
        sPw[prow * 64 + (((kvl >> 3) ^ pkey) << 3) + (kvl & 7)] = f2bf(p);
      }
#pragma unroll
      for (int d = 1; d < 16; d <<= 1) rs += __shfl_xor(rs, d);
      lr[r] += rs;
    }
    asm volatile("s_waitcnt lgkmcnt(0)" ::: "memory");

    // PV
    int rkey = (l15 ^ (l15 >> 2)) & 7;
    bf16x8 pa[2];
#pragma unroll
    for (int ks2 = 0; ks2 < 2; ks2++)
      pa[ks2] = *(const bf16x8*)&sPw[l15 * 64 + (((ks2 * 4 + l4) ^ rkey) << 3)];
    __builtin_amdgcn_s_setprio(1);
#pragma unroll
    for (int nf = 0; nf < 16; nf++) {
      int vr = nf * 16 + l15;
#pragma unroll
      for (int ks2 = 0; ks2 < 2; ks2++) {
        bf16x8 vf =
            *(const bf16x8*)&sV[vr * 64 + (((ks2 * 4 + l4) ^ (vr & 7)) * 8)];
        o[nf] = __builtin_amdgcn_mfma_f32_16x16x32_bf16(pa[ks2], vf, o[nf], 0, 0, 0);
      }
    }
    __builtin_amdgcn_s_setprio(0);
    asm volatile("s_barrier" ::: "memory");
  }

  float invl[4];
#pragma unroll
  for (int r = 0; r < 4; r++) invl[r] = 1.0f / lr[r];
#pragma unroll
  for (int nf = 0; nf < 16; nf++) {
    int d = nf * 16 + l15;
#pragma unroll
    for (int r = 0; r < 4; r++) {
      int qi = qbase + w * 16 + l4 * 4 + r;
      ctx[(size_t)(b * kS + qi) * kH + h * kHD + d] = f2bf(o[nf][r] * invl[r]);
    }
  }
#undef ATTN_STAGE
}

}  // namespace

extern "C" void kernel_launch(void* const* d_in, const int* in_sizes, int n_in,
                              void* d_out, int out_size, void* d_ws,
                              size_t ws_size, hipStream_t stream) {
  const float* x = (const float*)d_in[0];
  const int* amask = (const int*)d_in[1];
  const int* pos = (const int*)d_in[2];
  const float* lns = (const float*)d_in[3];
  const float* lnb = (const float*)d_in[4];
  const float* wq = (const float*)d_in[5];
  const float* wk = (const float*)d_in[6];
  const float* wv = (const float*)d_in[7];
  const float* wo = (const float*)d_in[8];
  const float* w_in = (const float*)d_in[9];
  const float* b_in = (const float*)d_in[10];
  const float* w_out = (const float*)d_in[11];
  const float* b_out = (const float*)d_in[12];
  float* out = (float*)d_out;

  if (ws_size < 268435456ull) return;  // need 256 MiB scratch
  char* ws = (char*)d_ws;
  unsigned short* h_bf = (unsigned short*)ws;                  // 32 MiB
  unsigned short* big = (unsigned short*)(ws + 33554432ull);   // 128 MiB
  unsigned short* vbuf = (unsigned short*)(ws + 167772160ull); // 32 MiB
  unsigned short* wbuf = (unsigned short*)(ws + 201326592ull); // 64 MiB
  unsigned short* mid = big;                    // [4096][16384] during MLP
  unsigned short* qbuf = big;                   // then q
  unsigned short* kbuf = big + 16777216;        // k
  unsigned short* vtb = big + 33554432;         // v^T [B,NH,HD,S]
  unsigned short* ctxb = vbuf;                  // ctx overwrites v after vtrans

  dim3 t256(256);
  dim3 t512(512);
  dim3 t32x8(32, 8);

  // 1. LayerNorm -> h (bf16); out = x
  ln_fwd<<<kB * kS, t256, 0, stream>>>(x, lns, lnb, h_bf, out);

  // 2. MLP first GEMM (two N-halves): mid = gelu(h @ w_in + b_in)
  for (int c = 0; c < 2; c++) {
    cvt_t<<<dim3(256, 128), t32x8, 0, stream>>>(w_in + c * 8192, 16384, wbuf, 4096);
    gemm256<1><<<dim3(512), t512, 0, stream>>>(
        h_bf, 4096, wbuf, 4096, mid + c * 8192, 16384, b_in + c * 8192, 4096, 32);
  }
  // 3. MLP second GEMM (two K-halves): out += mid @ w_out + b_out
  for (int c = 0; c < 2; c++) {
    cvt_t<<<dim3(128, 256), t32x8, 0, stream>>>(
        w_out + (size_t)c * 8192 * 4096, 4096, wbuf, 8192);
    if (c == 0)
      gemm256<3><<<dim3(256), t512, 0, stream>>>(mid + c * 8192, 16384, wbuf,
                                                 8192, out, 4096, b_out, 8192, 16);
    else
      gemm256<2><<<dim3(256), t512, 0, stream>>>(
          mid + c * 8192, 16384, wbuf, 8192, out, 4096, nullptr, 8192, 16);
  }

  // 4. QKV projections
  const float* wqkv[3] = {wq, wk, wv};
  unsigned short* qkvp[3] = {qbuf, kbuf, vbuf};
  for (int i = 0; i < 3; i++) {
    cvt_t<<<dim3(128, 128), t32x8, 0, stream>>>(wqkv[i], 4096, wbuf, 4096);
    gemm256<0><<<dim3(256), t512, 0, stream>>>(h_bf, 4096, wbuf, 4096,
                                               qkvp[i], 4096, nullptr, 4096, 16);
  }
  // 5. RoPE + scale q by 1/sqrt(HD)
  rope_scale<<<32768, t256, 0, stream>>>(qbuf, kbuf, pos);
  // 6. V transpose to [B,NH,HD,S]
  vtrans<<<dim3(64, 8, 32), t32x8, 0, stream>>>(vbuf, vtb);
  // 7. attention -> ctx (bf16)
  attn_fwd<<<dim3(512), t512, 0, stream>>>(qbuf, kbuf, vtb, amask, ctxb);
  // 8. out += ctx @ wo
  cvt_t<<<dim3(128, 128), t32x8, 0, stream>>>(wo, 4096, wbuf, 4096);
  gemm256<2><<<dim3(256), t512, 0, stream>>>(ctxb, 4096, wbuf, 4096, out,
                                             4096, nullptr, 4096, 16);
}

// Round 4
// 2005.132 us; speedup vs baseline: 1.6409x; 1.0373x over previous
//
#include <hip/hip_runtime.h>
#include <hip/hip_bf16.h>
#include <math.h>

namespace {

constexpr int kB = 2;
constexpr int kS = 2048;
constexpr int kH = 4096;
constexpr int kNH = 16;
constexpr int kHD = 256;

typedef __attribute__((ext_vector_type(4))) float f32x4;
typedef __attribute__((ext_vector_type(8))) short bf16x8;

__device__ __forceinline__ unsigned short f2bf(float f) {
  unsigned int u = __float_as_uint(f);
  u += 0x7FFFu + ((u >> 16) & 1u);
  return (unsigned short)(u >> 16);
}
__device__ __forceinline__ float bf2f(unsigned short h) {
  return __uint_as_float(((unsigned int)h) << 16);
}
__device__ __forceinline__ void gl2lds16(const void* g, void* l) {
  __builtin_amdgcn_global_load_lds(
      (const __attribute__((address_space(1))) unsigned int*)g,
      (__attribute__((address_space(3))) unsigned int*)l, 16, 0, 0);
}

// ---------------- LayerNorm: x -> h(bf16), out = x (residual init) ---------
__global__ __launch_bounds__(256) void ln_fwd(
    const float* __restrict__ x, const float* __restrict__ gam,
    const float* __restrict__ bet, unsigned short* __restrict__ hout,
    float* __restrict__ outp) {
  int row = blockIdx.x;
  int t = threadIdx.x;
  const float4* xr = (const float4*)(x + (size_t)row * kH);
  float4 v[4];
  float sum = 0.f, sq = 0.f;
#pragma unroll
  for (int i = 0; i < 4; i++) {
    v[i] = xr[t + i * 256];
    sum += v[i].x + v[i].y + v[i].z + v[i].w;
    sq += v[i].x * v[i].x + v[i].y * v[i].y + v[i].z * v[i].z + v[i].w * v[i].w;
  }
#pragma unroll
  for (int o = 32; o > 0; o >>= 1) {
    sum += __shfl_xor(sum, o);
    sq += __shfl_xor(sq, o);
  }
  __shared__ float red[8];
  if ((t & 63) == 0) { red[t >> 6] = sum; red[4 + (t >> 6)] = sq; }
  __syncthreads();
  sum = red[0] + red[1] + red[2] + red[3];
  sq = red[4] + red[5] + red[6] + red[7];
  float mu = sum * (1.f / kH);
  float rstd = rsqrtf(sq * (1.f / kH) - mu * mu + 1e-5f);
  const float4* gp = (const float4*)gam;
  const float4* bp = (const float4*)bet;
  ushort4* hr = (ushort4*)(hout + (size_t)row * kH);
  float4* orow = (float4*)(outp + (size_t)row * kH);
#pragma unroll
  for (int i = 0; i < 4; i++) {
    float4 g = gp[t + i * 256];
    float4 bb = bp[t + i * 256];
    ushort4 hv;
    hv.x = f2bf((v[i].x - mu) * rstd * g.x + bb.x);
    hv.y = f2bf((v[i].y - mu) * rstd * g.y + bb.y);
    hv.z = f2bf((v[i].z - mu) * rstd * g.z + bb.z);
    hv.w = f2bf((v[i].w - mu) * rstd * g.w + bb.w);
    hr[t + i * 256] = hv;
    orow[t + i * 256] = v[i];
  }
}

// ------- transpose-convert: out[n][k] = bf16(in[k][n]) ---------------------
__global__ __launch_bounds__(256) void cvt_t(
    const float* __restrict__ in, int ldin, unsigned short* __restrict__ outp,
    int ldout) {
  __shared__ float tile[32][33];
  int n0 = blockIdx.x * 32, k0 = blockIdx.y * 32;
  int tx = threadIdx.x, ty = threadIdx.y;
#pragma unroll
  for (int i = 0; i < 4; i++)
    tile[ty + i * 8][tx] = in[(size_t)(k0 + ty + i * 8) * ldin + n0 + tx];
  __syncthreads();
#pragma unroll
  for (int i = 0; i < 4; i++)
    outp[(size_t)(n0 + ty + i * 8) * ldout + k0 + tx] =
        f2bf(tile[tx][ty + i * 8]);
}

// ------- v [B,S,NH,HD] -> vt [B,NH,HD,S] (bf16) ----------------------------
__global__ __launch_bounds__(256) void vtrans(
    const unsigned short* __restrict__ v, unsigned short* __restrict__ vt) {
  __shared__ unsigned short tile[32][33];
  int bh = blockIdx.z;
  int s0 = blockIdx.x * 32, d0 = blockIdx.y * 32;
  int tx = threadIdx.x, ty = threadIdx.y;
  int b = bh >> 4, h = bh & 15;
  const unsigned short* src = v + (size_t)(b * kS) * kH + h * kHD;
#pragma unroll
  for (int i = 0; i < 4; i++)
    tile[ty + i * 8][tx] = src[(size_t)(s0 + ty + i * 8) * kH + d0 + tx];
  __syncthreads();
  unsigned short* dst = vt + (size_t)bh * kHD * kS;
#pragma unroll
  for (int i = 0; i < 4; i++)
    dst[(size_t)(d0 + ty + i * 8) * kS + s0 + tx] = tile[tx][ty + i * 8];
}

// ------- RoPE (pairs) + q-scale 1/16, in place -----------------------------
__global__ __launch_bounds__(256) void rope_scale(
    unsigned short* __restrict__ q, unsigned short* __restrict__ k,
    const int* __restrict__ pos) {
  int idx = blockIdx.x * 256 + threadIdx.x;  // pair index over B*S*NH*(HD/2)
  int j = idx & 127;
  int rowh = idx >> 7;  // b*S*NH + s*NH + h
  int h = rowh & 15;
  int s = (rowh >> 4) & 2047;
  int b = rowh >> 15;
  size_t off = ((size_t)(b * kS + s)) * kH + h * kHD + 2 * j;
  const float SCALE = 0.0625f;  // 1/sqrt(256)
  if (j < 32) {
    int p = pos[b * kS + s];
    float inv = exp2f(-(float)j * (13.287712379549449f / 32.f));  // 10000^(-j/32)
    float fr = (float)p * inv;
    float sn, cs;
    sincosf(fr, &sn, &cs);
    float e = bf2f(q[off]), o = bf2f(q[off + 1]);
    q[off] = f2bf((e * cs - o * sn) * SCALE);
    q[off + 1] = f2bf((o * cs + e * sn) * SCALE);
    e = bf2f(k[off]); o = bf2f(k[off + 1]);
    k[off] = f2bf(e * cs - o * sn);
    k[off + 1] = f2bf(o * cs + e * sn);
  } else {
    q[off] = f2bf(bf2f(q[off]) * SCALE);
    q[off + 1] = f2bf(bf2f(q[off + 1]) * SCALE);
  }
}

// ======= 256x256 GEMM, BK=64, 8 waves, 2-barrier/tile deep pipeline ========
// Per tile t: region1 {stage B(t+1) then AE/AL(t+1); read B + A-q0/q1;
// MFMA q0,q1}; vmcnt(8)[forces AL(t)]+barrier; region2 {A-q2/q3; MFMA q2,q3};
// lgkmcnt(0)+vmcnt(2)[forces B+AE(t+1), leaves AL(t+1)]+barrier.
#define AF_MMA(P)                                                           \
  {                                                                         \
    bf16x8 af_[2][2];                                                       \
    _Pragma("unroll") for (int fm = 0; fm < 2; fm++)                        \
        _Pragma("unroll") for (int kk = 0; kk < 2; kk++) {                  \
      int q_ = (2 * (P) + fm) * 16 + l15;                                   \
      af_[fm][kk] = *(const bf16x8*)(cur + ((q_ & 64) << 8) + wm * 8192 +   \
                                     ((q_ & 63) << 7) +                     \
                                     ((((kk << 2) | l4) ^ key) << 4));      \
    }                                                                       \
    __builtin_amdgcn_s_setprio(1);                                          \
    _Pragma("unroll") for (int fm = 0; fm < 2; fm++)                        \
        _Pragma("unroll") for (int fn = 0; fn < 4; fn++)                    \
            _Pragma("unroll") for (int kk = 0; kk < 2; kk++)                \
      acc[2 * (P) + fm][fn] = __builtin_amdgcn_mfma_f32_16x16x32_bf16(      \
          af_[fm][kk], bfr[fn][kk], acc[2 * (P) + fm][fn], 0, 0, 0);        \
    __builtin_amdgcn_s_setprio(0);                                          \
  }

template <int EPI>
__global__ __launch_bounds__(512, 2) void gemm256(
    const unsigned short* __restrict__ A, int lda,
    const unsigned short* __restrict__ Bt, int ldb, void* __restrict__ Cp,
    int ldc, const float* __restrict__ bias, int K, int gx) {
  __shared__ __align__(16) char lds[131072];
  const int t = threadIdx.x;
  const int lane = t & 63, w = t >> 6;
  const int wm = w >> 2, wn = w & 3;
  const int l15 = lane & 15, l4 = lane >> 4;
  const int key = l15 & 7;

  const int nwg = gridDim.x;
  const int orig = blockIdx.x;
  const int wg = (orig & 7) * (nwg >> 3) + (orig >> 3);  // XCD swizzle (nwg%8==0)
  const int bx = wg % gx, by = wg / gx;
  const int m0 = by * 256, n0 = bx * 256;

  const int lr = t >> 3, ch = t & 7;
  const int swk = (ch ^ (lr & 7)) * 8;
  const unsigned short* aE0 = A + (size_t)(m0 + lr) * lda + swk;
  const unsigned short* aE1 = A + (size_t)(m0 + 128 + lr) * lda + swk;
  const unsigned short* aL0 = A + (size_t)(m0 + 64 + lr) * lda + swk;
  const unsigned short* aL1 = A + (size_t)(m0 + 192 + lr) * lda + swk;
  const unsigned short* b00 = Bt + (size_t)(n0 + lr) * ldb + swk;
  const unsigned short* b01 = Bt + (size_t)(n0 + 64 + lr) * ldb + swk;
  const unsigned short* b10 = Bt + (size_t)(n0 + 128 + lr) * ldb + swk;
  const unsigned short* b11 = Bt + (size_t)(n0 + 192 + lr) * ldb + swk;
  const int t16 = t * 16;

  f32x4 acc[8][4];
#pragma unroll
  for (int m = 0; m < 8; m++)
#pragma unroll
    for (int n = 0; n < 4; n++) acc[m][n] = (f32x4)(0.f);

  // prologue: stage tile 0 (order: B x4, AE x2, AL x2)
  {
    char* b = lds;
    gl2lds16(b00, b + 32768 + t16); b00 += 64;
    gl2lds16(b01, b + 40960 + t16); b01 += 64;
    gl2lds16(b10, b + 49152 + t16); b10 += 64;
    gl2lds16(b11, b + 57344 + t16); b11 += 64;
    gl2lds16(aE0, b + t16);         aE0 += 64;
    gl2lds16(aE1, b + 8192 + t16);  aE1 += 64;
    gl2lds16(aL0, b + 16384 + t16); aL0 += 64;
    gl2lds16(aL1, b + 24576 + t16); aL1 += 64;
  }
  asm volatile("s_waitcnt vmcnt(2)" ::: "memory");  // B+AE resident
  asm volatile("s_barrier" ::: "memory");

  const int nt = K >> 6;
  for (int kt = 0; kt < nt; ++kt) {
    const char* cur = lds + (kt & 1) * 65536;
    char* nxt = lds + (((kt & 1) ^ 1)) * 65536;
    const bool pre = (kt + 1 < nt);
    bf16x8 bfr[4][2];
    // -------- region 1: stage B(t+1); read B-frags + A-q0; MFMA q0
    if (pre) {
      gl2lds16(b00, nxt + 32768 + t16); b00 += 64;
      gl2lds16(b01, nxt + 40960 + t16); b01 += 64;
      gl2lds16(b10, nxt + 49152 + t16); b10 += 64;
      gl2lds16(b11, nxt + 57344 + t16); b11 += 64;
    }
#pragma unroll
    for (int fn = 0; fn < 4; fn++)
#pragma unroll
      for (int kk = 0; kk < 2; kk++) {
        int n = wn * 64 + fn * 16 + l15;
        bfr[fn][kk] = *(const bf16x8*)(cur + 32768 + (n << 7) +
                                       ((((kk << 2) | l4) ^ key) << 4));
      }
    AF_MMA(0)
    // stage A(t+1); MFMA q1
    if (pre) {
      gl2lds16(aE0, nxt + t16);         aE0 += 64;
      gl2lds16(aE1, nxt + 8192 + t16);  aE1 += 64;
      gl2lds16(aL0, nxt + 16384 + t16); aL0 += 64;
      gl2lds16(aL1, nxt + 24576 + t16); aL1 += 64;
    }
    AF_MMA(1)
    if (pre) asm volatile("s_waitcnt vmcnt(8)" ::: "memory");  // forces AL(t)
    else     asm volatile("s_waitcnt vmcnt(0)" ::: "memory");
    asm volatile("s_barrier" ::: "memory");
    // -------- region 2: MFMA q2, q3 (read AL of cur)
    AF_MMA(2)
    AF_MMA(3)
    asm volatile("s_waitcnt lgkmcnt(0)" ::: "memory");
    if (pre) asm volatile("s_waitcnt vmcnt(2)" ::: "memory");  // B+AE(t+1)
    asm volatile("s_barrier" ::: "memory");
  }

  const int crow = m0 + wm * 128 + l4 * 4;
  const int ccol = n0 + wn * 64 + l15;
#pragma unroll
  for (int m = 0; m < 8; m++) {
#pragma unroll
    for (int n = 0; n < 4; n++) {
      int col = ccol + n * 16;
#pragma unroll
      for (int r = 0; r < 4; r++) {
        int row = crow + m * 16 + r;
        float v = acc[m][n][r];
        size_t idx = (size_t)row * ldc + col;
        if constexpr (EPI == 0) {
          ((unsigned short*)Cp)[idx] = f2bf(v);
        } else if constexpr (EPI == 1) {
          float u = v + bias[col];
          float c = 0.7978845608028654f * (u + 0.044715f * u * u * u);
          float g = u / (1.0f + __expf(-2.0f * c));
          ((unsigned short*)Cp)[idx] = f2bf(g);
        } else if constexpr (EPI == 2) {
          ((float*)Cp)[idx] += v;
        } else {
          ((float*)Cp)[idx] += v + bias[col];
        }
      }
    }
  }
}

// ======= flash attention v3: 8 waves, QBLK=128, KVBLK=64, pipelined ========
__global__ __launch_bounds__(512) void attn_fwd(
    const unsigned short* __restrict__ q, const unsigned short* __restrict__ k,
    const unsigned short* __restrict__ vt, const int* __restrict__ amask,
    unsigned short* __restrict__ ctx) {
  __shared__ __align__(16) char alds[147456];
  const int t = threadIdx.x, lane = t & 63, w = t >> 6;
  const int bid = blockIdx.x;
  const int qb = 15 - (bid >> 5);       // heavy-first
  const int bh = bid & 31;
  const int b = bh >> 4, h = bh & 15;
  const int l15 = lane & 15, l4 = lane >> 4;
  const int qbase = qb * 128;

  bf16x8 qf[8];
  {
    int qrow = qbase + w * 16 + l15;
    const unsigned short* qp =
        q + (size_t)(b * kS + qrow) * kH + h * kHD + l4 * 8;
#pragma unroll
    for (int ks = 0; ks < 8; ks++) qf[ks] = *(const bf16x8*)(qp + ks * 32);
  }
  f32x4 o[16];
#pragma unroll
  for (int nf = 0; nf < 16; nf++) o[nf] = (f32x4)(0.f);
  float mr[4] = {-INFINITY, -INFINITY, -INFINITY, -INFINITY};
  float lr[4] = {0.f, 0.f, 0.f, 0.f};

  const unsigned short* kbase = k + (size_t)(b * kS) * kH + h * kHD;
  const unsigned short* vbase = vt + (size_t)bh * kHD * kS;
  unsigned short* sPw = (unsigned short*)(alds + 131072 + w * 2048);
  const int nt = 2 * qb + 2;

  const int krow = t >> 5, kch = t & 31;
  const int kcs = (kch ^ (krow & 7)) * 8;
  const int vrow = t >> 3, vch = t & 7;
  const int vcs = (vch ^ (vrow & 7)) * 8;
  const int t16b = t * 16;

#define ATTN_STAGE(KV0, BUF)                                                 \
  {                                                                          \
    char* kd = alds + (BUF) * 32768;                                         \
    char* vd = alds + 65536 + (BUF) * 32768;                                 \
    _Pragma("unroll") for (int i = 0; i < 4; i++) {                          \
      gl2lds16(kbase + (size_t)((KV0) + krow + i * 16) * kH + kcs,           \
               kd + i * 8192 + t16b);                                        \
      gl2lds16(vbase + (size_t)(vrow + i * 64) * kS + (KV0) + vcs,           \
               vd + i * 8192 + t16b);                                        \
    }                                                                        \
  }

  ATTN_STAGE(0, 0)

  for (int kvt = 0; kvt < nt; kvt++) {
    const int kv0 = kvt * 64;
    const int cb = kvt & 1;
    if (kvt + 1 < nt) {
      ATTN_STAGE(kv0 + 64, cb ^ 1)
      asm volatile("s_waitcnt vmcnt(8)" ::: "memory");
    } else {
      asm volatile("s_waitcnt vmcnt(0)" ::: "memory");
    }
    asm volatile("s_barrier" ::: "memory");

    const unsigned short* sK = (const unsigned short*)(alds + cb * 32768);
    const unsigned short* sV =
        (const unsigned short*)(alds + 65536 + cb * 32768);

    f32x4 sc[4];
#pragma unroll
    for (int g = 0; g < 4; g++) sc[g] = (f32x4)(0.f);
    __builtin_amdgcn_s_setprio(1);
#pragma unroll
    for (int g = 0; g < 4; g++) {
      int row = g * 16 + l15;
#pragma unroll
      for (int ks = 0; ks < 8; ks++) {
        bf16x8 kf =
            *(const bf16x8*)&sK[row * 256 + (((ks * 4 + l4) ^ (row & 7)) * 8)];
        sc[g] = __builtin_amdgcn_mfma_f32_16x16x32_bf16(qf[ks], kf, sc[g], 0, 0, 0);
      }
    }
    __builtin_amdgcn_s_setprio(0);

    int am[4];
#pragma unroll
    for (int g = 0; g < 4; g++) am[g] = amask[b * kS + kv0 + g * 16 + l15];
    float mx[4];
#pragma unroll
    for (int r = 0; r < 4; r++) {
      int qi = qbase + w * 16 + l4 * 4 + r;
      float a = -INFINITY;
#pragma unroll
      for (int g = 0; g < 4; g++) {
        bool ok = (kv0 + g * 16 + l15 <= qi) && (am[g] != 0);
        float s = ok ? sc[g][r] : -INFINITY;
        sc[g][r] = s;
        a = fmaxf(a, s);
      }
#pragma unroll
      for (int d = 1; d < 16; d <<= 1) a = fmaxf(a, __shfl_xor(a, d));
      mx[r] = a;
    }
    bool nd = false;
#pragma unroll
    for (int r = 0; r < 4; r++) nd |= (mx[r] > mr[r] + 8.f);
    if (__any(nd)) {
#pragma unroll
      for (int r = 0; r < 4; r++) {
        float nm = fmaxf(mr[r], mx[r]);
        float c = __expf(mr[r] - nm);
        lr[r] *= c;
        mr[r] = nm;
#pragma unroll
        for (int nf = 0; nf < 16; nf++) o[nf][r] *= c;
      }
    }
#pragma unroll
    for (int r = 0; r < 4; r++) {
      int prow = l4 * 4 + r;
      int pkey = (prow ^ (prow >> 2)) & 7;
      float rs = 0.f;
#pragma unroll
      for (int g = 0; g < 4; g++) {
        float p = __expf(sc[g][r] - mr[r]);
        rs += p;
        int kvl = g * 16 + l15;
        sPw[prow * 64 + (((kvl >> 3) ^ pkey) << 3) + (kvl & 7)] = f2bf(p);
      }
#pragma unroll
      for (int d = 1; d < 16; d <<= 1) rs += __shfl_xor(rs, d);
      lr[r] += rs;
    }
    asm volatile("s_waitcnt lgkmcnt(0)" ::: "memory");

    int rkey = (l15 ^ (l15 >> 2)) & 7;
    bf16x8 pa[2];
#pragma unroll
    for (int ks2 = 0; ks2 < 2; ks2++)
      pa[ks2] = *(const bf16x8*)&sPw[l15 * 64 + (((ks2 * 4 + l4) ^ rkey) << 3)];
    __builtin_amdgcn_s_setprio(1);
#pragma unroll
    for (int nf = 0; nf < 16; nf++) {
      int vr = nf * 16 + l15;
#pragma unroll
      for (int ks2 = 0; ks2 < 2; ks2++) {
        bf16x8 vf =
            *(const bf16x8*)&sV[vr * 64 + (((ks2 * 4 + l4) ^ (vr & 7)) * 8)];
        o[nf] = __builtin_amdgcn_mfma_f32_16x16x32_bf16(pa[ks2], vf, o[nf], 0, 0, 0);
      }
    }
    __builtin_amdgcn_s_setprio(0);
    asm volatile("s_barrier" ::: "memory");
  }

  float invl[4];
#pragma unroll
  for (int r = 0; r < 4; r++) invl[r] = 1.0f / lr[r];
#pragma unroll
  for (int nf = 0; nf < 16; nf++) {
    int d = nf * 16 + l15;
#pragma unroll
    for (int r = 0; r < 4; r++) {
      int qi = qbase + w * 16 + l4 * 4 + r;
      ctx[(size_t)(b * kS + qi) * kH + h * kHD + d] = f2bf(o[nf][r] * invl[r]);
    }
  }
#undef ATTN_STAGE
}

}  // namespace

extern "C" void kernel_launch(void* const* d_in, const int* in_sizes, int n_in,
                              void* d_out, int out_size, void* d_ws,
                              size_t ws_size, hipStream_t stream) {
  const float* x = (const float*)d_in[0];
  const int* amask = (const int*)d_in[1];
  const int* pos = (const int*)d_in[2];
  const float* lns = (const float*)d_in[3];
  const float* lnb = (const float*)d_in[4];
  const float* wq = (const float*)d_in[5];
  const float* wk = (const float*)d_in[6];
  const float* wv = (const float*)d_in[7];
  const float* wo = (const float*)d_in[8];
  const float* w_in = (const float*)d_in[9];
  const float* b_in = (const float*)d_in[10];
  const float* w_out = (const float*)d_in[11];
  const float* b_out = (const float*)d_in[12];
  float* out = (float*)d_out;

  if (ws_size < 268435456ull) return;  // need 256 MiB scratch
  char* ws = (char*)d_ws;
  unsigned short* h_bf = (unsigned short*)ws;                  // 32 MiB
  unsigned short* big = (unsigned short*)(ws + 33554432ull);   // 128 MiB
  unsigned short* vbuf = (unsigned short*)(ws + 167772160ull); // 32 MiB
  unsigned short* wbuf = (unsigned short*)(ws + 201326592ull); // 64 MiB
  unsigned short* mid = big;                    // [4096][16384] during MLP
  unsigned short* qbuf = big;                   // then q
  unsigned short* kbuf = big + 16777216;        // k
  unsigned short* vtb = big + 33554432;         // v^T [B,NH,HD,S]
  unsigned short* ctxb = vbuf;                  // ctx overwrites v after vtrans

  dim3 t256(256);
  dim3 t512(512);
  dim3 t32x8(32, 8);

  // 1. LayerNorm -> h (bf16); out = x
  ln_fwd<<<kB * kS, t256, 0, stream>>>(x, lns, lnb, h_bf, out);

  // 2. MLP first GEMM (two N-halves): mid = gelu(h @ w_in + b_in)
  for (int c = 0; c < 2; c++) {
    cvt_t<<<dim3(256, 128), t32x8, 0, stream>>>(w_in + c * 8192, 16384, wbuf, 4096);
    gemm256<1><<<dim3(512), t512, 0, stream>>>(
        h_bf, 4096, wbuf, 4096, mid + c * 8192, 16384, b_in + c * 8192, 4096, 32);
  }
  // 3. MLP second GEMM (two K-halves): out += mid @ w_out + b_out
  for (int c = 0; c < 2; c++) {
    cvt_t<<<dim3(128, 256), t32x8, 0, stream>>>(
        w_out + (size_t)c * 8192 * 4096, 4096, wbuf, 8192);
    if (c == 0)
      gemm256<3><<<dim3(256), t512, 0, stream>>>(mid + c * 8192, 16384, wbuf,
                                                 8192, out, 4096, b_out, 8192, 16);
    else
      gemm256<2><<<dim3(256), t512, 0, stream>>>(
          mid + c * 8192, 16384, wbuf, 8192, out, 4096, nullptr, 8192, 16);
  }

  // 4. QKV projections
  const float* wqkv[3] = {wq, wk, wv};
  unsigned short* qkvp[3] = {qbuf, kbuf, vbuf};
  for (int i = 0; i < 3; i++) {
    cvt_t<<<dim3(128, 128), t32x8, 0, stream>>>(wqkv[i], 4096, wbuf, 4096);
    gemm256<0><<<dim3(256), t512, 0, stream>>>(h_bf, 4096, wbuf, 4096,
                                               qkvp[i], 4096, nullptr, 4096, 16);
  }
  // 5. RoPE + scale q by 1/sqrt(HD)
  rope_scale<<<32768, t256, 0, stream>>>(qbuf, kbuf, pos);
  // 6. V transpose to [B,NH,HD,S]
  vtrans<<<dim3(64, 8, 32), t32x8, 0, stream>>>(vbuf, vtb);
  // 7. attention -> ctx (bf16)
  attn_fwd<<<dim3(512), t512, 0, stream>>>(qbuf, kbuf, vtb, amask, ctxb);
  // 8. out += ctx @ wo
  cvt_t<<<dim3(128, 128), t32x8, 0, stream>>>(wo, 4096, wbuf, 4096);
  gemm256<2><<<dim3(256), t512, 0, stream>>>(ctxb, 4096, wbuf, 4096, out,
                                             4096, nullptr, 4096, 16);
}